// Round 2
// baseline (1482.273 us; speedup 1.0000x reference)
//
#include <hip/hip_runtime.h>

typedef unsigned int   u32;
typedef unsigned long long u64;

// ---------------- helpers ----------------
__device__ __forceinline__ float fast_tanh(float x) {
    x = fminf(fmaxf(x, -15.f), 15.f);
    float e = __expf(2.f * x);
    return __fdividef(e - 1.f, e + 1.f);
}
__device__ __forceinline__ float fast_sigmoid(float x) {
    x = fminf(fmaxf(x, -30.f), 30.f);
    return __fdividef(1.f, 1.f + __expf(-x));
}

// ---------------- workspace layout (bytes, all fp32) ----------------
// x: 256x400; xg: 256x3200 (shared L0/L1); hist: 2x256x400 u64 (shared, tag-versioned);
// x1: 256x800; hV: 256x800; P: 256x1600 (later LF); Q: 256x1600 (later U). Total 10.24 MB.
#define OF_X    ((size_t)0)
#define OF_XG   (OF_X  + 409600)
#define OF_H    (OF_XG + 3276800)
#define OF_X1   (OF_H  + 1638400)
#define OF_HV   (OF_X1 + 819200)
#define OF_P    (OF_HV + 819200)
#define OF_Q    (OF_P  + 1638400)

// ---------------- embedding ----------------
__global__ void embed_kernel(const int* __restrict__ words, const int* __restrict__ tags,
                             const float* __restrict__ wemb, const float* __restrict__ temb,
                             float* __restrict__ x) {
    int t = blockIdx.x;
    int w = words[t], tg = tags[t];
    for (int i = threadIdx.x; i < 400; i += 256) {
        float v = (i < 300) ? wemb[(size_t)w * 300 + i]
                            : temb[(size_t)tg * 100 + (i - 300)];
        x[(size_t)t * 400 + i] = v;
    }
}

// ---------------- tiled GEMM: C[t][n] = act( sum_k A[t][k]*B[n*ldb+boff+k] + b1[n]+b2[n] )
// grid (M/32, N/64), block 256. All fp32. act: 0 none, 1 tanh.
__global__ __launch_bounds__(256)
void gemm_kernel(const float* __restrict__ A, int lda,
                 const float* __restrict__ B, int ldb, int boff,
                 const float* __restrict__ bias1, const float* __restrict__ bias2,
                 float* __restrict__ C, int ldc, int K, int act) {
    int t0 = blockIdx.x * 32;
    int n0 = blockIdx.y * 64;
    int tid = threadIdx.x;
    __shared__ float A_l[16][36];
    __shared__ float B_l[16][68];
    float acc[2][4] = {{0.f,0.f,0.f,0.f},{0.f,0.f,0.f,0.f}};
    int ty = tid >> 4;           // rows ty*2, ty*2+1
    int tx = tid & 15;           // cols tx*4..tx*4+3
    int kk_a = tid & 15, tt_a = tid >> 4;
    int nn_b = tid >> 2, kk4_b = (tid & 3) * 4;

    for (int k0 = 0; k0 < K; k0 += 16) {
        A_l[kk_a][tt_a]      = A[(size_t)(t0 + tt_a) * lda + k0 + kk_a];
        A_l[kk_a][tt_a + 16] = A[(size_t)(t0 + tt_a + 16) * lda + k0 + kk_a];
        float4 bv = *(const float4*)(B + (size_t)(n0 + nn_b) * ldb + boff + k0 + kk4_b);
        B_l[kk4_b + 0][nn_b] = bv.x;
        B_l[kk4_b + 1][nn_b] = bv.y;
        B_l[kk4_b + 2][nn_b] = bv.z;
        B_l[kk4_b + 3][nn_b] = bv.w;
        __syncthreads();
        #pragma unroll
        for (int kk = 0; kk < 16; ++kk) {
            float a0 = A_l[kk][ty * 2], a1 = A_l[kk][ty * 2 + 1];
            float b0 = B_l[kk][tx * 4 + 0], b1 = B_l[kk][tx * 4 + 1];
            float b2 = B_l[kk][tx * 4 + 2], b3 = B_l[kk][tx * 4 + 3];
            acc[0][0] += a0 * b0; acc[0][1] += a0 * b1; acc[0][2] += a0 * b2; acc[0][3] += a0 * b3;
            acc[1][0] += a1 * b0; acc[1][1] += a1 * b1; acc[1][2] += a1 * b2; acc[1][3] += a1 * b3;
        }
        __syncthreads();
    }
    float bs[4];
    #pragma unroll
    for (int j = 0; j < 4; ++j) {
        int n = n0 + tx * 4 + j;
        float b = 0.f;
        if (bias1) b += bias1[n];
        if (bias2) b += bias2[n];
        bs[j] = b;
    }
    #pragma unroll
    for (int i = 0; i < 2; ++i) {
        int t = t0 + ty * 2 + i;
        #pragma unroll
        for (int j = 0; j < 4; ++j) {
            float v = acc[i][j] + bs[j];
            if (act) v = fast_tanh(v);
            C[(size_t)t * ldc + n0 + tx * 4 + j] = v;
        }
    }
}

// ---------------- persistent distributed LSTM layer ----------------
// grid 2*50 blocks, 256 threads. Block (d,wg) owns h-slice [wg*8, wg*8+8) -> 32 gate rows.
// LDS weights fp32: 32 rows x 400 cols = 51.2 KB. Step sync via tag-carrying u64 atomics:
// hist[d][t][j] = (u64(tag_base+t+1)<<32) | f32bits(h). hist zeroed at launch.
#define LSTM_G 50
__global__ __launch_bounds__(256)
void lstm_kernel(const float* __restrict__ Whh,   // (2,1600,400)
                 const float* __restrict__ h0,    // (4,400)
                 const float* __restrict__ c0,    // (4,400)
                 int hc_base,
                 const float* __restrict__ xg,    // (256,3200): [t][d*1600 + gaterow]
                 u64* __restrict__ hist,          // (2,256,400)
                 u32 tag_base) {
    const int T = 256;
    int bid = blockIdx.x;
    int d  = bid / LSTM_G;
    int wg = bid % LSTM_G;
    int a8 = wg * 8;
    int tid = threadIdx.x;
    int wave = tid >> 6, lane = tid & 63;
    int half = lane >> 5, rr = lane & 31;   // rr: gate row within our 32

    __shared__ float2 w2[200 * 32];   // [kpair][row]
    __shared__ float  h_lds[400];
    __shared__ float  partials[8 * 32];

    // load weights: row rr -> global gate row gr = (rr>>3)*400 + a8 + (rr&7)
    for (int idx = tid; idx < 6400; idx += 256) {
        int cp = idx >> 5, row = idx & 31;
        int gr = ((row >> 3) * 400) + a8 + (row & 7);
        const float* wp = Whh + (size_t)d * 640000 + (size_t)gr * 400 + 2 * cp;
        w2[idx] = make_float2(wp[0], wp[1]);
    }
    float c_state = 0.f;
    if (tid < 8) c_state = c0[(hc_base + d) * 400 + a8 + tid];

    u64* hst = hist + (size_t)d * 102400;
    __syncthreads();

    for (int t = 0; t < T; ++t) {
        // prefetch xg for our 32 gate rows (wave0 lanes 0..31)
        float xgv = 0.f;
        if (tid < 32) {
            int gr = ((rr >> 3) * 400) + a8 + (rr & 7);
            int xt = d ? (T - 1 - t) : t;
            xgv = xg[(size_t)xt * 3200 + d * 1600 + gr];
        }
        // stage h_prev into LDS
        if (t == 0) {
            for (int j = tid; j < 400; j += 256)
                h_lds[j] = h0[(hc_base + d) * 400 + j];
        } else {
            const u64* src = hst + (size_t)(t - 1) * 400;
            u32 want = tag_base + (u32)t;
            int j1 = tid, j2 = tid + 256;
            bool d1 = false, d2 = (j2 >= 400);
            while (!(d1 && d2)) {
                if (!d1) {
                    u64 v = __hip_atomic_load(&src[j1], __ATOMIC_RELAXED, __HIP_MEMORY_SCOPE_AGENT);
                    if ((u32)(v >> 32) == want) { h_lds[j1] = __uint_as_float((u32)v); d1 = true; }
                }
                if (!d2) {
                    u64 v = __hip_atomic_load(&src[j2], __ATOMIC_RELAXED, __HIP_MEMORY_SCOPE_AGENT);
                    if ((u32)(v >> 32) == want) { h_lds[j2] = __uint_as_float((u32)v); d2 = true; }
                }
            }
        }
        __syncthreads();

        // dot: (wave,half) covers k in [wave*100 + half*50, +50)
        int kb0 = wave * 50 + half * 25;
        const float2* h2 = (const float2*)h_lds;
        float sum = 0.f;
        #pragma unroll
        for (int kk = 0; kk < 25; ++kk) {
            float2 wv = w2[(kb0 + kk) * 32 + rr];
            float2 hv = h2[kb0 + kk];
            sum += wv.x * hv.x + wv.y * hv.y;
        }
        partials[(wave * 2 + half) * 32 + rr] = sum;
        __syncthreads();

        if (wave == 0) {
            float tot = xgv;
            #pragma unroll
            for (int s = 0; s < 8; ++s) tot += partials[s * 32 + rr];
            int gate = rr >> 3;
            float v = (gate == 2) ? fast_tanh(tot) : fast_sigmoid(tot);
            int j = rr & 7;
            float fv = __shfl(v, 8 + j);
            float gv = __shfl(v, 16 + j);
            float ov = __shfl(v, 24 + j);
            if (lane < 8) {
                c_state = fv * c_state + v * gv;   // v = i-gate on lanes 0..7
                float h = ov * fast_tanh(c_state);
                u64 pk = (((u64)(tag_base + t + 1)) << 32) | (u64)__float_as_uint(h);
                __hip_atomic_store(&hst[(size_t)t * 400 + a8 + lane], pk,
                                   __ATOMIC_RELAXED, __HIP_MEMORY_SCOPE_AGENT);
            }
        }
    }
}

// ---------------- gathers ----------------
__global__ void gather_bi_kernel(const u64* __restrict__ hist, float* __restrict__ out800) {
    int t = blockIdx.x;
    for (int c = threadIdx.x; c < 800; c += 256) {
        u64 v = (c < 400) ? hist[(size_t)t * 400 + c]
                          : hist[(size_t)102400 + (size_t)(255 - t) * 400 + (c - 400)];
        out800[(size_t)t * 800 + c] = __uint_as_float((u32)v);
    }
}
__global__ void gather_lf_kernel(const float* __restrict__ hV, const int* __restrict__ arcs,
                                 float* __restrict__ LF) {
    int t = blockIdx.x;
    int head = arcs[1 + t];
    int idxt = min(max(head - 1, 0), 255);
    for (int c = threadIdx.x; c < 1600; c += 256) {
        float v = (c < 800) ? hV[(size_t)t * 800 + c] : hV[(size_t)idxt * 800 + (c - 800)];
        LF[(size_t)t * 1600 + c] = v;
    }
}

// ---------------- arc pairwise scorer ----------------
// raw[i,j] = ba2 + sum_m Wa2[m]*tanh(P[i][m]+Q[j][m]); diag 0; out[(i+1)*257+(j+1)]
__global__ __launch_bounds__(256)
void arc_kernel(const float* __restrict__ P, const float* __restrict__ Q,
                const float* __restrict__ Wa2, const float* __restrict__ ba2,
                float* __restrict__ out) {
    int i0 = blockIdx.x * 16, j0 = blockIdx.y * 16;
    int tid = threadIdx.x;
    int ii = tid >> 4, jj = tid & 15;
    __shared__ float Pt[16][65], Qt[16][65];
    __shared__ float W2f[1600];
    for (int m = tid; m < 1600; m += 256) W2f[m] = Wa2[m];
    __syncthreads();

    float acc = 0.f;
    int mm = tid & 63, r4 = tid >> 6;
    for (int m0 = 0; m0 < 1600; m0 += 64) {
        #pragma unroll
        for (int rr = r4; rr < 16; rr += 4) {
            Pt[rr][mm] = P[(size_t)(i0 + rr) * 1600 + m0 + mm];
            Qt[rr][mm] = Q[(size_t)(j0 + rr) * 1600 + m0 + mm];
        }
        __syncthreads();
        #pragma unroll 8
        for (int m = 0; m < 64; ++m) {
            float s = Pt[ii][m] + Qt[jj][m];
            acc += W2f[m0 + m] * fast_tanh(s);
        }
        __syncthreads();
    }
    float raw = acc + ba2[0];
    int gi = i0 + ii, gj = j0 + jj;
    if (gi == gj) raw = 0.f;
    out[(size_t)(gi + 1) * 257 + (gj + 1)] = raw;
}

__global__ void border_kernel(float* __restrict__ out) {
    int t = threadIdx.x;
    if (t < 257) out[t] = (t == 0) ? 1.0f : 0.0f;          // row 0
    if (t >= 1 && t < 257) out[(size_t)t * 257] = 0.0f;    // col 0
}

// ---------------- label output ----------------
__global__ __launch_bounds__(256)
void label_out_kernel(const float* __restrict__ U, const float* __restrict__ Wl2,
                      const float* __restrict__ bl2, const int* __restrict__ arcs,
                      float* __restrict__ out) {
    int t = blockIdx.x;
    __shared__ float u_l[1600];
    __shared__ float part[4][64];
    for (int m = threadIdx.x; m < 1600; m += 256) u_l[m] = U[(size_t)t * 1600 + m];
    __syncthreads();
    int tid = threadIdx.x;
    int n = tid & 63, p = tid >> 6;
    float acc = 0.f;
    if (n < 40) {
        const float4* wr4 = (const float4*)(Wl2 + (size_t)n * 1600 + p * 400);
        const float*  ub  = u_l + p * 400;
        for (int m = 0; m < 100; ++m) {
            float4 w = wr4[m];
            acc += ub[4*m] * w.x + ub[4*m+1] * w.y + ub[4*m+2] * w.z + ub[4*m+3] * w.w;
        }
    }
    part[p][n] = acc;
    __syncthreads();
    if (tid < 40) {
        float v = part[0][tid] + part[1][tid] + part[2][tid] + part[3][tid] + bl2[tid];
        if (arcs[1 + t] == 0) v = 0.f;
        out[(size_t)t * 40 + tid] = v;
    }
}

// ---------------- launch ----------------
extern "C" void kernel_launch(void* const* d_in, const int* in_sizes, int n_in,
                              void* d_out, int out_size, void* d_ws, size_t ws_size,
                              hipStream_t stream) {
    const int*   words = (const int*)d_in[0];
    const int*   tags  = (const int*)d_in[1];
    const int*   arcs  = (const int*)d_in[2];
    const float* h0    = (const float*)d_in[3];
    const float* c0    = (const float*)d_in[4];
    const float* wemb  = (const float*)d_in[5];
    const float* temb  = (const float*)d_in[6];
    const float* Wih0  = (const float*)d_in[7];
    const float* Whh0  = (const float*)d_in[8];
    const float* bih0  = (const float*)d_in[9];
    const float* bhh0  = (const float*)d_in[10];
    const float* Wih1  = (const float*)d_in[11];
    const float* Whh1  = (const float*)d_in[12];
    const float* bih1  = (const float*)d_in[13];
    const float* bhh1  = (const float*)d_in[14];
    const float* Wa1   = (const float*)d_in[15];
    const float* ba1   = (const float*)d_in[16];
    const float* Wa2   = (const float*)d_in[17];
    const float* ba2   = (const float*)d_in[18];
    const float* Wl1   = (const float*)d_in[19];
    const float* bl1   = (const float*)d_in[20];
    const float* Wl2   = (const float*)d_in[21];
    const float* bl2   = (const float*)d_in[22];
    float* out = (float*)d_out;

    char* ws = (char*)d_ws;
    float* x    = (float*)(ws + OF_X);
    float* xg   = (float*)(ws + OF_XG);
    u64*   hist = (u64*)  (ws + OF_H);
    float* x1   = (float*)(ws + OF_X1);
    float* hV   = (float*)(ws + OF_HV);
    float* P    = (float*)(ws + OF_P);
    float* Q    = (float*)(ws + OF_Q);
    float* LF   = P;   // alias: P dead after arc_kernel
    float* U    = Q;   // alias: Q dead after arc_kernel

    // zero hist so tag-polling never depends on workspace poison
    hipMemsetAsync(hist, 0, 1638400, stream);

    embed_kernel<<<256, 256, 0, stream>>>(words, tags, wemb, temb, x);
    gemm_kernel<<<dim3(8, 50), 256, 0, stream>>>(x, 400, Wih0, 400, 0, bih0, bhh0, xg, 3200, 400, 0);
    lstm_kernel<<<2 * LSTM_G, 256, 0, stream>>>(Whh0, h0, c0, 0, xg, hist, 0u);
    gather_bi_kernel<<<256, 256, 0, stream>>>(hist, x1);
    gemm_kernel<<<dim3(8, 50), 256, 0, stream>>>(x1, 800, Wih1, 800, 0, bih1, bhh1, xg, 3200, 800, 0);
    lstm_kernel<<<2 * LSTM_G, 256, 0, stream>>>(Whh1, h0, c0, 2, xg, hist, 256u);
    gather_bi_kernel<<<256, 256, 0, stream>>>(hist, hV);
    gemm_kernel<<<dim3(8, 25), 256, 0, stream>>>(hV, 800, Wa1, 1600, 0,   ba1,    nullptr, P, 1600, 800, 0);
    gemm_kernel<<<dim3(8, 25), 256, 0, stream>>>(hV, 800, Wa1, 1600, 800, nullptr, nullptr, Q, 1600, 800, 0);
    arc_kernel<<<dim3(16, 16), 256, 0, stream>>>(P, Q, Wa2, ba2, out);
    border_kernel<<<1, 320, 0, stream>>>(out);
    gather_lf_kernel<<<256, 256, 0, stream>>>(hV, arcs, LF);
    gemm_kernel<<<dim3(8, 25), 256, 0, stream>>>(LF, 1600, Wl1, 1600, 0, bl1, nullptr, U, 1600, 1600, 1);
    label_out_kernel<<<256, 256, 0, stream>>>(U, Wl2, bl2, arcs, out + 66049);
}